// Round 1
// baseline (1781.819 us; speedup 1.0000x reference)
//
#include <hip/hip_runtime.h>

#define DM 1024
#define NH 16
#define HD 64
#define BB 2
#define SS 2048
#define MROWS (BB*SS)   // 4096

typedef __attribute__((ext_vector_type(8))) short s16x8;
typedef __attribute__((ext_vector_type(4))) float f32x4;

__device__ __forceinline__ float bf2f(unsigned short u) {
  return __uint_as_float(((unsigned int)u) << 16);
}
__device__ __forceinline__ unsigned short f2bf(float f) {
  unsigned int x = __float_as_uint(f);
  unsigned int r = (x + 0x7FFFu + ((x >> 16) & 1u)) >> 16;
  return (unsigned short)r;
}

// ---------------- f32 -> bf16 convert ----------------
__global__ void cvt_f32_bf16(const float* __restrict__ in,
                             unsigned short* __restrict__ out, int n) {
  int i = (blockIdx.x * blockDim.x + threadIdx.x) * 4;
  if (i >= n) return;
  float4 v = *(const float4*)(in + i);
  ushort4 o;
  o.x = f2bf(v.x); o.y = f2bf(v.y); o.z = f2bf(v.z); o.w = f2bf(v.w);
  *(ushort4*)(out + i) = o;
}

// ---------------- bf16 MFMA GEMM: C[M][N] = A[M][K] @ BT[N][K]^T + bias ----------------
#define TM 128
#define TN 128
#define BK 32

__global__ __launch_bounds__(256) void gemm_bt_bias(
    const unsigned short* __restrict__ A,   // [M][K] bf16
    const unsigned short* __restrict__ BT,  // [N][K] bf16
    const float* __restrict__ bias,         // [N]
    float* __restrict__ C,                  // [M][N] f32
    int M, int N, int K)
{
  __shared__ __align__(16) unsigned short As[TM][BK];
  __shared__ __align__(16) unsigned short Bs[TN][BK];

  const int tid  = threadIdx.x;
  const int lane = tid & 63;
  const int wave = tid >> 6;
  const int bm = blockIdx.y * TM;
  const int bn = blockIdx.x * TN;
  const int wm = (wave >> 1) * 64;
  const int wn = (wave & 1) * 64;

  const int sr = tid >> 2;        // 0..63 staging row
  const int sk = (tid & 3) * 8;   // 0,8,16,24

  const int fr = lane & 15;       // fragment row/col
  const int fq = lane >> 4;       // 0..3

  f32x4 acc[4][4] = {};

  const unsigned short* Ap = A + (long)(bm + sr) * K + sk;
  const unsigned short* Bp = BT + (long)(bn + sr) * K + sk;

  for (int kt = 0; kt < K; kt += BK) {
    s16x8 a0 = *(const s16x8*)(Ap + kt);
    s16x8 a1 = *(const s16x8*)(Ap + 64L * K + kt);
    s16x8 b0 = *(const s16x8*)(Bp + kt);
    s16x8 b1 = *(const s16x8*)(Bp + 64L * K + kt);
    __syncthreads();
    *(s16x8*)&As[sr][sk]      = a0;
    *(s16x8*)&As[sr + 64][sk] = a1;
    *(s16x8*)&Bs[sr][sk]      = b0;
    *(s16x8*)&Bs[sr + 64][sk] = b1;
    __syncthreads();
    s16x8 af[4], bfr[4];
    #pragma unroll
    for (int m = 0; m < 4; ++m) af[m]  = *(const s16x8*)&As[wm + m*16 + fr][fq*8];
    #pragma unroll
    for (int n = 0; n < 4; ++n) bfr[n] = *(const s16x8*)&Bs[wn + n*16 + fr][fq*8];
    #pragma unroll
    for (int m = 0; m < 4; ++m)
      #pragma unroll
      for (int n = 0; n < 4; ++n)
        acc[m][n] = __builtin_amdgcn_mfma_f32_16x16x32_bf16(af[m], bfr[n], acc[m][n], 0, 0, 0);
  }

  #pragma unroll
  for (int m = 0; m < 4; ++m) {
    int row = bm + wm + m*16 + fq*4;
    #pragma unroll
    for (int n = 0; n < 4; ++n) {
      int col = bn + wn + n*16 + fr;
      float bv = bias[col];
      float* cp = C + (long)row * N + col;
      #pragma unroll
      for (int i = 0; i < 4; ++i)
        cp[(long)i * N] = acc[m][n][i] + bv;
    }
  }
}

// ---------------- RoPE + split into Q,K,V [B][H][S][64] bf16 (Q pre-scaled 1/8) ----------------
__global__ void rope_split(const float* __restrict__ qkv,       // [4096][3072]
                           unsigned short* __restrict__ Qb,
                           unsigned short* __restrict__ Kb,
                           unsigned short* __restrict__ Vb)
{
  int t = blockIdx.x * blockDim.x + threadIdx.x;  // B*H*S*32 = 2097152
  int d  = t & 31;
  int s  = (t >> 5) & (SS - 1);
  int bh = t >> 16;           // b*16 + h
  int h  = bh & 15;
  long row = (long)(bh >> 4) * SS + s;
  const float* base = qkv + row * 3072 + h * 64;
  float q1 = base[d],        q2 = base[d + 32];
  float k1 = base[1024 + d], k2 = base[1024 + d + 32];
  float v1 = base[2048 + d], v2 = base[2048 + d + 32];
  float inv = powf(10000.0f, -(float)d * (1.0f / 32.0f));
  float ang = (float)s * inv;
  float c = cosf(ang), sn = sinf(ang);
  long o = ((long)bh * SS + s) * 64;
  const float qs = 0.125f;   // 1/sqrt(64)
  Qb[o + d]      = f2bf((q1 * c - q2 * sn) * qs);
  Qb[o + d + 32] = f2bf((q1 * sn + q2 * c) * qs);
  Kb[o + d]      = f2bf(k1 * c - k2 * sn);
  Kb[o + d + 32] = f2bf(k1 * sn + k2 * c);
  Vb[o + d]      = f2bf(v1);
  Vb[o + d + 32] = f2bf(v2);
}

// ---------------- causal flash attention, fp32 VALU ----------------
// block = 1 wave (64 threads); thread owns one q-row; grid (32 qtiles, 32 bh)
#define KVT 32
__global__ __launch_bounds__(64) void attn_flash(
    const unsigned short* __restrict__ Qb,
    const unsigned short* __restrict__ Kb,
    const unsigned short* __restrict__ Vb,
    unsigned short* __restrict__ O)        // [B][S][1024] bf16
{
  __shared__ __align__(16) float Ks[KVT][68];
  __shared__ __align__(16) float Vs[KVT][68];
  int bh = blockIdx.y;
  int qt = gridDim.x - 1 - blockIdx.x;   // big tiles first
  int lane = threadIdx.x;
  int qrow = qt * 64 + lane;

  const unsigned short* Qp = Qb + ((long)bh * SS + qrow) * 64;
  float q[64];
  #pragma unroll
  for (int v = 0; v < 8; ++v) {
    s16x8 r = *(const s16x8*)(Qp + v * 8);
    #pragma unroll
    for (int j = 0; j < 8; ++j) q[v * 8 + j] = bf2f((unsigned short)r[j]);
  }
  float o[64];
  #pragma unroll
  for (int d = 0; d < 64; ++d) o[d] = 0.f;
  float mval = -INFINITY, l = 0.f;

  int nkt = 2 * qt + 2;   // 32-key tiles covering keys 0 .. qt*64+63
  for (int kt = 0; kt < nkt; ++kt) {
    {
      int r = lane & 31;
      const unsigned short* src = ((lane < 32) ? Kb : Vb) + ((long)bh * SS + kt * KVT + r) * 64;
      float* dst = (lane < 32) ? &Ks[r][0] : &Vs[r][0];
      __syncthreads();
      #pragma unroll
      for (int v = 0; v < 8; ++v) {
        s16x8 rw = *(const s16x8*)(src + v * 8);
        #pragma unroll
        for (int j = 0; j < 8; ++j) dst[v * 8 + j] = bf2f((unsigned short)rw[j]);
      }
      __syncthreads();
    }
    int kbase = kt * KVT;
    #pragma unroll 1
    for (int j0 = 0; j0 < KVT; j0 += 16) {
      float sc[16];
      float tmax = -INFINITY;
      #pragma unroll
      for (int jj = 0; jj < 16; ++jj) {
        int j = j0 + jj;
        float s = 0.f;
        const float4* kr = (const float4*)&Ks[j][0];
        #pragma unroll
        for (int dd = 0; dd < 16; ++dd) {
          float4 kv = kr[dd];
          s += q[dd*4+0]*kv.x + q[dd*4+1]*kv.y + q[dd*4+2]*kv.z + q[dd*4+3]*kv.w;
        }
        if (kbase + j > qrow) s = -INFINITY;
        sc[jj] = s;
        tmax = fmaxf(tmax, s);
      }
      if (tmax > mval) {             // per-lane online-softmax rescale
        float corr = __expf(mval - tmax);
        l *= corr;
        #pragma unroll
        for (int d = 0; d < 64; ++d) o[d] *= corr;
        mval = tmax;
      }
      #pragma unroll
      for (int jj = 0; jj < 16; ++jj) {
        float p = __expf(sc[jj] - mval);
        l += p;
        const float4* vr = (const float4*)&Vs[j0 + jj][0];
        #pragma unroll
        for (int dd = 0; dd < 16; ++dd) {
          float4 vv = vr[dd];
          o[dd*4+0] += p*vv.x; o[dd*4+1] += p*vv.y; o[dd*4+2] += p*vv.z; o[dd*4+3] += p*vv.w;
        }
      }
    }
  }

  float inv_l = 1.0f / l;
  int b = bh >> 4, h = bh & 15;
  unsigned short* Op = O + ((long)b * SS + qrow) * DM + h * 64;
  #pragma unroll
  for (int v = 0; v < 8; ++v) {
    s16x8 w;
    #pragma unroll
    for (int j = 0; j < 8; ++j) w[j] = (short)f2bf(o[v * 8 + j] * inv_l);
    *(s16x8*)(Op + v * 8) = w;
  }
}

// ---------------- launch ----------------
extern "C" void kernel_launch(void* const* d_in, const int* in_sizes, int n_in,
                              void* d_out, int out_size, void* d_ws, size_t ws_size,
                              hipStream_t stream)
{
  const float* x     = (const float*)d_in[0];
  const float* qkv_w = (const float*)d_in[1];
  const float* qkv_b = (const float*)d_in[2];
  const float* out_w = (const float*)d_in[3];
  const float* out_b = (const float*)d_in[4];
  float* out = (float*)d_out;

  char* ws = (char*)d_ws;
  unsigned short* x_bf    = (unsigned short*)(ws);               // 8,388,608 B
  unsigned short* w1_bf   = (unsigned short*)(ws + 8388608);     // 6,291,456 B
  unsigned short* w2_bf   = (unsigned short*)(ws + 14680064);    // 2,097,152 B
  float*          qkv32   = (float*)         (ws + 16777216);    // 50,331,648 B
  unsigned short* Qb      = (unsigned short*)(ws + 67108864);    // 8,388,608 B
  unsigned short* Kb      = (unsigned short*)(ws + 75497472);    // 8,388,608 B
  unsigned short* Vb      = (unsigned short*)(ws + 83886080);    // 8,388,608 B
  unsigned short* attn_bf = (unsigned short*)(ws + 92274688);    // 8,388,608 B -> 100,663,296 total

  cvt_f32_bf16<<<4194304 / 4 / 256, 256, 0, stream>>>(x, x_bf, 4194304);
  cvt_f32_bf16<<<3145728 / 4 / 256, 256, 0, stream>>>(qkv_w, w1_bf, 3145728);
  cvt_f32_bf16<<<1048576 / 4 / 256, 256, 0, stream>>>(out_w, w2_bf, 1048576);

  gemm_bt_bias<<<dim3(3072 / TN, 4096 / TM), 256, 0, stream>>>(
      x_bf, w1_bf, qkv_b, qkv32, MROWS, 3 * DM, DM);

  rope_split<<<2097152 / 256, 256, 0, stream>>>(qkv32, Qb, Kb, Vb);

  attn_flash<<<dim3(32, 32), 64, 0, stream>>>(Qb, Kb, Vb, attn_bf);

  gemm_bt_bias<<<dim3(1024 / TN, 4096 / TM), 256, 0, stream>>>(
      attn_bf, w2_bf, out_b, out, MROWS, DM, DM);
}

// Round 5
// 287.630 us; speedup vs baseline: 6.1948x; 6.1948x over previous
//
#include <hip/hip_runtime.h>

#define DM 1024
#define NH 16
#define HD 64
#define BB 2
#define SS 2048
#define MROWS (BB*SS)   // 4096

typedef __attribute__((ext_vector_type(8))) short s16x8;
typedef __attribute__((ext_vector_type(4))) float f32x4;

__device__ __forceinline__ float bf2f(unsigned short u) {
  return __uint_as_float(((unsigned int)u) << 16);
}
__device__ __forceinline__ unsigned short f2bf(float f) {
  unsigned int x = __float_as_uint(f);
  unsigned int r = (x + 0x7FFFu + ((x >> 16) & 1u)) >> 16;
  return (unsigned short)r;
}

// ---------------- f32 -> bf16 convert ----------------
__global__ void cvt_f32_bf16(const float* __restrict__ in,
                             unsigned short* __restrict__ out, int n) {
  int i = (blockIdx.x * blockDim.x + threadIdx.x) * 4;
  if (i >= n) return;
  float4 v = *(const float4*)(in + i);
  ushort4 o;
  o.x = f2bf(v.x); o.y = f2bf(v.y); o.z = f2bf(v.z); o.w = f2bf(v.w);
  *(ushort4*)(out + i) = o;
}

// ---------------- bf16 MFMA GEMM: C[M][N] = A[M][K] @ BT[N][K]^T + bias ----------------
#define TM 128
#define TN 128
#define BK 32

__global__ __launch_bounds__(256) void gemm_bt_bias(
    const unsigned short* __restrict__ A,   // [M][K] bf16
    const unsigned short* __restrict__ BT,  // [N][K] bf16
    const float* __restrict__ bias,         // [N]
    float* __restrict__ C,                  // [M][N] f32
    int M, int N, int K)
{
  __shared__ __align__(16) unsigned short As[TM][BK];
  __shared__ __align__(16) unsigned short Bs[TN][BK];

  const int tid  = threadIdx.x;
  const int lane = tid & 63;
  const int wave = tid >> 6;
  const int bm = blockIdx.y * TM;
  const int bn = blockIdx.x * TN;
  const int wm = (wave >> 1) * 64;
  const int wn = (wave & 1) * 64;

  const int sr = tid >> 2;        // 0..63 staging row
  const int sk = (tid & 3) * 8;   // 0,8,16,24

  const int fr = lane & 15;       // fragment row/col
  const int fq = lane >> 4;       // 0..3

  f32x4 acc[4][4] = {};

  const unsigned short* Ap = A + (long)(bm + sr) * K + sk;
  const unsigned short* Bp = BT + (long)(bn + sr) * K + sk;

  for (int kt = 0; kt < K; kt += BK) {
    s16x8 a0 = *(const s16x8*)(Ap + kt);
    s16x8 a1 = *(const s16x8*)(Ap + 64L * K + kt);
    s16x8 b0 = *(const s16x8*)(Bp + kt);
    s16x8 b1 = *(const s16x8*)(Bp + 64L * K + kt);
    __syncthreads();
    *(s16x8*)&As[sr][sk]      = a0;
    *(s16x8*)&As[sr + 64][sk] = a1;
    *(s16x8*)&Bs[sr][sk]      = b0;
    *(s16x8*)&Bs[sr + 64][sk] = b1;
    __syncthreads();
    s16x8 af[4], bfr[4];
    #pragma unroll
    for (int m = 0; m < 4; ++m) af[m]  = *(const s16x8*)&As[wm + m*16 + fr][fq*8];
    #pragma unroll
    for (int n = 0; n < 4; ++n) bfr[n] = *(const s16x8*)&Bs[wn + n*16 + fr][fq*8];
    #pragma unroll
    for (int m = 0; m < 4; ++m)
      #pragma unroll
      for (int n = 0; n < 4; ++n)
        acc[m][n] = __builtin_amdgcn_mfma_f32_16x16x32_bf16(af[m], bfr[n], acc[m][n], 0, 0, 0);
  }

  #pragma unroll
  for (int m = 0; m < 4; ++m) {
    int row = bm + wm + m*16 + fq*4;
    #pragma unroll
    for (int n = 0; n < 4; ++n) {
      int col = bn + wn + n*16 + fr;
      float bv = bias[col];
      float* cp = C + (long)row * N + col;
      #pragma unroll
      for (int i = 0; i < 4; ++i)
        cp[(long)i * N] = acc[m][n][i] + bv;
    }
  }
}

// ---------------- RoPE + split into Q,K,V [B*H][S][64] bf16 (Q pre-scaled 1/8) ----------------
__global__ void rope_split(const float* __restrict__ qkv,       // [4096][3072]
                           unsigned short* __restrict__ Qb,
                           unsigned short* __restrict__ Kb,
                           unsigned short* __restrict__ Vb)
{
  int t = blockIdx.x * blockDim.x + threadIdx.x;  // B*H*S*32 = 2097152
  int d  = t & 31;
  int s  = (t >> 5) & (SS - 1);
  int bh = t >> 16;           // b*16 + h
  int h  = bh & 15;
  long row = (long)(bh >> 4) * SS + s;
  const float* base = qkv + row * 3072 + h * 64;
  float q1 = base[d],        q2 = base[d + 32];
  float k1 = base[1024 + d], k2 = base[1024 + d + 32];
  float v1 = base[2048 + d], v2 = base[2048 + d + 32];
  float inv = powf(10000.0f, -(float)d * (1.0f / 32.0f));
  float ang = (float)s * inv;
  float c = cosf(ang), sn = sinf(ang);
  long o = ((long)bh * SS + s) * 64;
  const float qs = 0.125f;   // 1/sqrt(64)
  Qb[o + d]      = f2bf((q1 * c - q2 * sn) * qs);
  Qb[o + d + 32] = f2bf((q1 * sn + q2 * c) * qs);
  Kb[o + d]      = f2bf(k1 * c - k2 * sn);
  Kb[o + d + 32] = f2bf(k1 * sn + k2 * c);
  Vb[o + d]      = f2bf(v1);
  Vb[o + d + 32] = f2bf(v2);
}

// ---------------- V transpose: Vb [bh][s][64] -> Vt [bh][64][s] ----------------
__global__ __launch_bounds__(256) void transpose_v(const unsigned short* __restrict__ Vb,
                                                   unsigned short* __restrict__ Vt)
{
  __shared__ unsigned short T[64][65];
  int bh = blockIdx.y;
  int s0 = blockIdx.x * 64;
  int tid = threadIdx.x;
  int r  = tid >> 2;          // 0..63
  int cc = (tid & 3) * 16;    // 0,16,32,48
  const unsigned short* src = Vb + ((long)bh * SS + s0 + r) * 64 + cc;
  s16x8 a0 = *(const s16x8*)src;
  s16x8 a1 = *(const s16x8*)(src + 8);
  #pragma unroll
  for (int i = 0; i < 8; ++i) T[cc + i][r]     = (unsigned short)a0[i];
  #pragma unroll
  for (int i = 0; i < 8; ++i) T[cc + 8 + i][r] = (unsigned short)a1[i];
  __syncthreads();
  unsigned short* dst = Vt + ((long)bh * 64 + r) * SS + s0 + cc;
  s16x8 w0, w1;
  #pragma unroll
  for (int i = 0; i < 8; ++i) w0[i] = (short)T[r][cc + i];
  #pragma unroll
  for (int i = 0; i < 8; ++i) w1[i] = (short)T[r][cc + 8 + i];
  *(s16x8*)dst = w0;
  *(s16x8*)(dst + 8) = w1;
}

// ---------------- causal flash attention, MFMA 16x16x32 ----------------
// block = 4 waves; wave owns 16 q rows; block covers 64 q rows x 2 paired q-tiles.
// Swapped QK^T: S^T = mfma(K,Q) so k-reduction is shfl-free-ish; P through
// per-wave swizzled LDS (no barriers); K/V fragments read straight from L2.
__global__ __launch_bounds__(256) void attn_mfma(
    const unsigned short* __restrict__ Qb,  // [32][2048][64] (q pre-scaled 1/8)
    const unsigned short* __restrict__ Kb,  // [32][2048][64]
    const unsigned short* __restrict__ Vt,  // [32][64][2048]
    unsigned short* __restrict__ O)         // [2][2048][1024] bf16
{
  __shared__ __align__(16) unsigned short Pbuf[4][1024];  // per-wave 16x64 bf16, swizzled
  const int bh   = blockIdx.y;
  const int bx   = blockIdx.x;       // 0..15
  const int tid  = threadIdx.x;
  const int lane = tid & 63;
  const int w    = tid >> 6;
  const int c    = lane & 15;        // C-layout col (q for S^T, d for O)
  const int g    = lane >> 4;        // 0..3
  const long bq  = (long)bh * SS * 64;
  const unsigned short* Kbh = Kb + bq;
  const unsigned short* Vbh = Vt + bq;
  char* Pw = (char*)&Pbuf[w][0];
  const int swz = (c & 7) << 4;
  const int b = bh >> 4, h = bh & 15;

  #pragma unroll 1
  for (int half = 0; half < 2; ++half) {
    const int qt    = half ? (31 - bx) : bx;
    const int qbase = qt * 64;
    const int qrow  = qbase + w * 16 + c;   // this lane's q (col role)
    const unsigned short* Qp = Qb + bq + (long)qrow * 64 + g * 8;
    s16x8 qf0 = *(const s16x8*)(Qp);
    s16x8 qf1 = *(const s16x8*)(Qp + 32);

    f32x4 of[4] = {};                 // O accum: row=q(g*4+i), col=d(c)+dt*16
    float m_old = -1e30f, lsum = 0.f;

    const int nkt = qt + 1;
    #pragma unroll 1
    for (int kt = 0; kt < nkt; ++kt) {
      const int kbase = kt * 64;
      const unsigned short* Kp = Kbh + (long)(kbase + c) * 64 + g * 8;
      f32x4 st[4];
      #pragma unroll
      for (int t = 0; t < 4; ++t) {
        s16x8 k0 = *(const s16x8*)(Kp + t * 1024);
        s16x8 k1 = *(const s16x8*)(Kp + t * 1024 + 32);
        f32x4 z = {0.f, 0.f, 0.f, 0.f};
        z = __builtin_amdgcn_mfma_f32_16x16x32_bf16(k0, qf0, z, 0, 0, 0);
        st[t] = __builtin_amdgcn_mfma_f32_16x16x32_bf16(k1, qf1, z, 0, 0, 0);
      }
      if (kt == nkt - 1) {            // diagonal tile: causal mask
        #pragma unroll
        for (int t = 0; t < 4; ++t)
          #pragma unroll
          for (int i = 0; i < 4; ++i)
            if (kbase + t * 16 + g * 4 + i > qrow) st[t][i] = -1e30f;
      }
      // row max over the 16 local scores, then across the 4 lane-groups
      float tmax = fmaxf(fmaxf(st[0][0], st[0][1]), fmaxf(st[0][2], st[0][3]));
      #pragma unroll
      for (int t = 1; t < 4; ++t)
        tmax = fmaxf(tmax, fmaxf(fmaxf(st[t][0], st[t][1]), fmaxf(st[t][2], st[t][3])));
      tmax = fmaxf(tmax, __shfl_xor(tmax, 16));
      tmax = fmaxf(tmax, __shfl_xor(tmax, 32));
      const float m_new = fmaxf(m_old, tmax);
      const float corr = __expf(m_old - m_new);
      m_old = m_new;
      lsum *= corr;
      float cr[4];
      #pragma unroll
      for (int i = 0; i < 4; ++i) cr[i] = __shfl(corr, g * 4 + i);
      #pragma unroll
      for (int dt = 0; dt < 4; ++dt)
        #pragma unroll
        for (int i = 0; i < 4; ++i) of[dt][i] *= cr[i];

      // P = exp(S - m), pack bf16, stage through swizzled per-wave LDS
      #pragma unroll
      for (int t = 0; t < 4; ++t) {
        float p0 = __expf(st[t][0] - m_new);
        float p1 = __expf(st[t][1] - m_new);
        float p2 = __expf(st[t][2] - m_new);
        float p3 = __expf(st[t][3] - m_new);
        lsum += (p0 + p1) + (p2 + p3);
        ushort4 pk;
        pk.x = f2bf(p0); pk.y = f2bf(p1); pk.z = f2bf(p2); pk.w = f2bf(p3);
        *(ushort4*)(Pw + ((c * 128 + t * 32 + g * 8) ^ swz)) = pk;
      }
      s16x8 pf0 = *(const s16x8*)(Pw + ((c * 128 +  0 + g * 16) ^ swz));
      s16x8 pf1 = *(const s16x8*)(Pw + ((c * 128 + 64 + g * 16) ^ swz));

      const unsigned short* Vp = Vbh + (long)c * SS + kbase + g * 8;
      #pragma unroll
      for (int dt = 0; dt < 4; ++dt) {
        s16x8 v0 = *(const s16x8*)(Vp + (long)dt * 16 * SS);
        s16x8 v1 = *(const s16x8*)(Vp + (long)dt * 16 * SS + 32);
        of[dt] = __builtin_amdgcn_mfma_f32_16x16x32_bf16(pf0, v0, of[dt], 0, 0, 0);
        of[dt] = __builtin_amdgcn_mfma_f32_16x16x32_bf16(pf1, v1, of[dt], 0, 0, 0);
      }
    }

    // epilogue: 1/l per q row, write O
    float L = lsum;
    L += __shfl_xor(L, 16);
    L += __shfl_xor(L, 32);
    float inv = 1.0f / L;
    float ir[4];
    #pragma unroll
    for (int i = 0; i < 4; ++i) ir[i] = __shfl(inv, g * 4 + i);
    #pragma unroll
    for (int i = 0; i < 4; ++i) {
      int q = qbase + w * 16 + g * 4 + i;
      unsigned short* Op = O + ((long)b * SS + q) * DM + h * 64 + c;
      #pragma unroll
      for (int dt = 0; dt < 4; ++dt)
        Op[dt * 16] = f2bf(of[dt][i] * ir[i]);
    }
  }
}

// ---------------- launch ----------------
extern "C" void kernel_launch(void* const* d_in, const int* in_sizes, int n_in,
                              void* d_out, int out_size, void* d_ws, size_t ws_size,
                              hipStream_t stream)
{
  const float* x     = (const float*)d_in[0];
  const float* qkv_w = (const float*)d_in[1];
  const float* qkv_b = (const float*)d_in[2];
  const float* out_w = (const float*)d_in[3];
  const float* out_b = (const float*)d_in[4];
  float* out = (float*)d_out;

  char* ws = (char*)d_ws;
  unsigned short* x_bf    = (unsigned short*)(ws);               // 8 MB
  unsigned short* w1_bf   = (unsigned short*)(ws + 8388608);     // 6 MB
  unsigned short* w2_bf   = (unsigned short*)(ws + 14680064);    // 2 MB
  unsigned short* Vt      = (unsigned short*)(ws + 16777216);    // 8 MB (overlaps qkv32 head; safe: used after rope_split)
  float*          qkv32   = (float*)         (ws + 16777216);    // 48 MB region (only live gemm1 -> rope_split)
  unsigned short* Qb      = (unsigned short*)(ws + 67108864);    // 8 MB
  unsigned short* Kb      = (unsigned short*)(ws + 75497472);    // 8 MB
  unsigned short* Vb      = (unsigned short*)(ws + 83886080);    // 8 MB
  unsigned short* attn_bf = (unsigned short*)(ws + 92274688);    // 8 MB -> 100,663,296 total

  cvt_f32_bf16<<<4194304 / 4 / 256, 256, 0, stream>>>(x, x_bf, 4194304);
  cvt_f32_bf16<<<3145728 / 4 / 256, 256, 0, stream>>>(qkv_w, w1_bf, 3145728);
  cvt_f32_bf16<<<1048576 / 4 / 256, 256, 0, stream>>>(out_w, w2_bf, 1048576);

  gemm_bt_bias<<<dim3(3072 / TN, 4096 / TM), 256, 0, stream>>>(
      x_bf, w1_bf, qkv_b, qkv32, MROWS, 3 * DM, DM);

  rope_split<<<2097152 / 256, 256, 0, stream>>>(qkv32, Qb, Kb, Vb);

  transpose_v<<<dim3(32, 32), 256, 0, stream>>>(Vb, Vt);

  attn_mfma<<<dim3(16, 32), 256, 0, stream>>>(Qb, Kb, Vt, attn_bf);

  gemm_bt_bias<<<dim3(1024 / TN, 4096 / TM), 256, 0, stream>>>(
      attn_bf, w2_bf, out_b, out, MROWS, DM, DM);
}